// Round 5
// baseline (261.552 us; speedup 1.0000x reference)
//
#include <hip/hip_runtime.h>
#include <cstddef>

#define NPB  4096            // points per batch
#define KNB  20              // neighbors
#define NB   8               // batches
#define NPTS (NB * NPB)      // 32768 total points
#define NSEG 8               // segment-waves per block
#define SEGW 512             // candidates per segment
#define NSLOT 16             // push-buffer slots per thread

// ---------------------------------------------------------------------------
// Kernel A+P: pack (x,y,z,xx) float4 (512 KB, L2-resident) + block 0 folds
// BN into conv weights. xx arithmetic identical to reference numpy fp32.
// (R9-validated)
// ---------------------------------------------------------------------------
__global__ __launch_bounds__(256) void pack_prep_kernel(
    const float* __restrict__ x, float4* __restrict__ xp,
    const float* __restrict__ w1, const float* __restrict__ b1,
    const float* __restrict__ g1, const float* __restrict__ be1,
    const float* __restrict__ rm1, const float* __restrict__ rv1,
    const float* __restrict__ w2, const float* __restrict__ b2,
    const float* __restrict__ g2, const float* __restrict__ be2,
    const float* __restrict__ rm2, const float* __restrict__ rv2,
    float* __restrict__ w1f, float* __restrict__ w2f, float* __restrict__ w2b)
{
    const int tid = threadIdx.x;
    const int g = blockIdx.x * 256 + tid;
    const int b = g >> 12, n = g & (NPB - 1);
    const float* xb = x + (size_t)b * 3 * NPB;
    float a0 = xb[n], a1 = xb[NPB + n], a2 = xb[2 * NPB + n];
    float xx = __fadd_rn(__fadd_rn(__fmul_rn(a0, a0), __fmul_rn(a1, a1)),
                         __fmul_rn(a2, a2));
    xp[g] = make_float4(a0, a1, a2, xx);

    if (blockIdx.x == 0) {
        if (tid < 64) {
            float sc1 = g1[tid] * rsqrtf(rv1[tid] + 1e-5f);
            float sh1 = be1[tid] - rm1[tid] * sc1;
#pragma unroll
            for (int j = 0; j < 6; ++j) w1f[tid * 8 + j] = sc1 * w1[tid * 6 + j];
            w1f[tid * 8 + 6] = sc1 * b1[tid] + sh1;
            w1f[tid * 8 + 7] = 0.f;
            float sc2 = g2[tid] * rsqrtf(rv2[tid] + 1e-5f);
            w2b[tid] = sc2 * b2[tid] + (be2[tid] - rm2[tid] * sc2);
        }
        for (int i = tid; i < 64 * 128; i += 256) {
            int c = i >> 6, o = i & 63;
            float sc2 = g2[o] * rsqrtf(rv2[o] + 1e-5f);
            w2f[i] = sc2 * w2[o * 128 + c];
        }
    }
}

// ---------------------------------------------------------------------------
// Kernel B+C merged. R14: index-carrying selection network.
// Each thread keeps (val[20], idx[20]); sort-step = cmp + max/min + 2 cndmask.
// Push gate d >= thr (thr = max over cross-wave vmins <= global t) keeps the
// per-segment lists EXACT under the total order (value desc, idx asc), so the
// 8-list merge directly yields the global top-20 indices in jax.lax.top_k
// order — phase B re-scan and dedup are deleted.
// ---------------------------------------------------------------------------
union KSMem {
    int2 pbuf[NSLOT][512];              // 64 KB scan push pairs {d_bits, idx}
    struct {
        float vals[NSEG][KNB][64];      // 40 KB sorted value lists
        unsigned short id16[NSEG][KNB][64];  // 20 KB matching index lists
    } m;                                // 60 KB
    struct {
        float cat[128 * 64];            // 32 KB [c][pt]: c<64 m1, c>=64 m2
        float dif[KNB][3][64];          // 15 KB [k][coord][pt]
    } f;                                // 47 KB  (union = 64 KB)
};

__global__ __launch_bounds__(512, 4) void knnfuse_kernel(
    const float4* __restrict__ xp,
    const float* __restrict__ w1f, const float* __restrict__ w2f,
    const float* __restrict__ w2b, float* __restrict__ out)
{
    __shared__ KSMem sm;
    __shared__ float share[NSEG][64];          // 2 KB cross-wave vmins
    __shared__ unsigned short outk[KNB][64];   // 2.5 KB final neighbor idx

    const int tid  = threadIdx.x;
    const int wv   = __builtin_amdgcn_readfirstlane(tid >> 6);
    const int lane = tid & 63;
    const int g0   = blockIdx.x * 64;
    const int b    = g0 >> 12;
    const int n0   = g0 & (NPB - 1);

    share[wv][lane] = -INFINITY;
    __syncthreads();

    const float4 me = xp[g0 + lane];                 // coalesced
    const float cx = me.x, cy = me.y, cz = me.z, xxn = me.w;

    auto dist = [&](float4 q) -> float {
        float inner = __fadd_rn(__fadd_rn(__fmul_rn(cx, q.x), __fmul_rn(cy, q.y)),
                                __fmul_rn(cz, q.z));
        return __fsub_rn(__fsub_rn(__fmul_rn(2.0f, inner), xxn), q.w);
    };

    float val[KNB];
    int   idx[KNB];
#pragma unroll
    for (int j = 0; j < KNB; ++j) { val[j] = -INFINITY; idx[j] = 0; }

    const int ibase = wv * SEGW;                     // uniform
    const float4* cand = xp + (b << 12) + ibase;     // wave-uniform -> s_load

    // (value,idx) sorted insert; strict > keeps earlier (lower idx) first on
    // ties -> lists are sorted by (value desc, idx asc). 5 VALU ops/slot.
    auto insert = [&](float cv, int ci) {
#pragma unroll
        for (int j = 0; j < KNB; ++j) {
            bool  c  = cv > val[j];
            float nv = fmaxf(cv, val[j]);
            float nm = fminf(cv, val[j]);
            int   ni = c ? ci : idx[j];
            int   nc = c ? idx[j] : ci;
            val[j] = nv; idx[j] = ni; cv = nm; ci = nc;
        }
    };

    // warm-up: direct sorted insert of first 20 candidates (1-ahead prefetch)
    {
        float4 cw = cand[0];
#pragma unroll 1
        for (int i = 0; i < KNB; ++i) {
            float4 nxt = cand[i + 1];                // i+1 <= 20 < SEGW: safe
            insert(dist(cw), ibase + i);
            cw = nxt;
        }
    }
    float vmin = val[KNB - 1];
    float thr  = vmin;
    int   cnt  = 0;

    // early cross-wave thr seed (racy: stale/-INF = safe, monotone)
    share[wv][lane] = vmin;
    {
        float mx = share[0][lane];
#pragma unroll
        for (int w = 1; w < NSEG; ++w) mx = fmaxf(mx, share[w][lane]);
        thr = fmaxf(thr, mx);
    }

    auto flush = [&]() {
        int2 cvp = sm.pbuf[0][tid];                  // speculative 1-ahead
#pragma unroll
        for (int j = 0; j < NSLOT; ++j) {
            if (!__any(j < cnt)) break;
            int2 nxt = (j + 1 < NSLOT) ? sm.pbuf[j + 1][tid]
                                       : make_int2(0, 0);
            float cv = (j < cnt) ? __int_as_float(cvp.x) : -INFINITY;
            insert(cv, cvp.y);                       // cv=-INF -> no-op
            cvp = nxt;
        }
        vmin = val[KNB - 1];
        cnt = 0;
        thr = fmaxf(thr, vmin);
    };

    // remainder of first 64-cand chunk, buffered (<=12 resident + 4 = 16)
    {
        float4 c4[4];
#pragma unroll
        for (int u = 0; u < 4; ++u) c4[u] = cand[KNB + u];
#pragma unroll 1
        for (int i = KNB; i < 64; i += 4) {
            float4 n4[4];
            const int nx = (i + 4 < 64) ? i + 4 : KNB;   // clamp: safe reload
#pragma unroll
            for (int u = 0; u < 4; ++u) n4[u] = cand[nx + u];
#pragma unroll
            for (int u = 0; u < 4; ++u) {
                float d = dist(c4[u]);
                if (d >= thr) {
                    sm.pbuf[cnt][tid] = make_int2(__float_as_int(d), ibase + i + u);
                    ++cnt;
                }
            }
            if (__any(cnt >= 13)) flush();
#pragma unroll
            for (int u = 0; u < 4; ++u) c4[u] = n4[u];
        }
    }
    flush();                                         // leave cnt=0 for main

    // main scan: threshold refresh every 32, flush check every 8,
    // ping-pong 8-wide candidate prefetch across the backedge
    {
        float4 ca[8], cb[8];
#pragma unroll
        for (int u = 0; u < 8; ++u) ca[u] = cand[64 + u];
#pragma unroll 1
        for (int i = 64; i < SEGW; i += 16) {
#pragma unroll
            for (int u = 0; u < 8; ++u) cb[u] = cand[i + 8 + u];
            if ((i & 31) == 0) {
                share[wv][lane] = vmin;              // racy: stale = safe
                float mx = share[0][lane];
#pragma unroll
                for (int w = 1; w < NSEG; ++w) mx = fmaxf(mx, share[w][lane]);
                thr = fmaxf(thr, mx);
            }
#pragma unroll
            for (int u = 0; u < 8; ++u) {
                float d = dist(ca[u]);
                if (d >= thr) {
                    sm.pbuf[cnt][tid] = make_int2(__float_as_int(d), ibase + i + u);
                    ++cnt;
                }
            }
            if (__any(cnt >= 9)) flush();            // <=8 resident + 8 = 16
            const int nx = (i + 16 < SEGW) ? i + 16 : 64;  // clamp: safe
#pragma unroll
            for (int u = 0; u < 8; ++u) ca[u] = cand[nx + u];
#pragma unroll
            for (int u = 0; u < 8; ++u) {
                float d = dist(cb[u]);
                if (d >= thr) {
                    sm.pbuf[cnt][tid] = make_int2(__float_as_int(d), ibase + i + 8 + u);
                    ++cnt;
                }
            }
            if (__any(cnt >= 9)) flush();
        }
    }
    flush();
    __syncthreads();                                 // retire push buffers

#pragma unroll
    for (int j = 0; j < KNB; ++j) {
        sm.m.vals[wv][j][lane] = val[j];
        sm.m.id16[wv][j][lane] = (unsigned short)idx[j];
    }
    __syncthreads();

    // all waves redundantly merge the 8 sorted (value,idx) lists -> outk.
    // Heads compared strict->: on value tie the lower wave (= lower global
    // index) wins; within a list ties are already idx-ascending. Result is
    // exactly jax.lax.top_k order (value desc, index asc).
    {
        int p0 = 0, p1 = 0, p2 = 0, p3 = 0, p4 = 0, p5 = 0, p6 = 0, p7 = 0;
#pragma unroll 1
        for (int k = 0; k < KNB; ++k) {
            float e0 = sm.m.vals[0][p0][lane], e1 = sm.m.vals[1][p1][lane];
            float e2 = sm.m.vals[2][p2][lane], e3 = sm.m.vals[3][p3][lane];
            float e4 = sm.m.vals[4][p4][lane], e5 = sm.m.vals[5][p5][lane];
            float e6 = sm.m.vals[6][p6][lane], e7 = sm.m.vals[7][p7][lane];
            float bv = e0; int bs = 0, bp = p0;
            if (e1 > bv) { bv = e1; bs = 1; bp = p1; }
            if (e2 > bv) { bv = e2; bs = 2; bp = p2; }
            if (e3 > bv) { bv = e3; bs = 3; bp = p3; }
            if (e4 > bv) { bv = e4; bs = 4; bp = p4; }
            if (e5 > bv) { bv = e5; bs = 5; bp = p5; }
            if (e6 > bv) { bv = e6; bs = 6; bp = p6; }
            if (e7 > bv) { bv = e7; bs = 7; bp = p7; }
            outk[k][lane] = sm.m.id16[bs][bp][lane];
            p0 += (bs == 0); p1 += (bs == 1); p2 += (bs == 2); p3 += (bs == 3);
            p4 += (bs == 4); p5 += (bs == 5); p6 += (bs == 6); p7 += (bs == 7);
        }
    }
    __syncthreads();                                 // outk ready; m dead

    // ------------------- fused conv epilogue (R9-validated) -----------------
#pragma unroll
    for (int r = 0; r < 3; ++r) {
        int p = tid + r * 512;
        if (p < KNB * 64) {
            int k = p >> 6, pt = p & 63;
            int nb = outk[k][pt];
            float4 nq = xp[(b << 12) + nb];              // scattered (spread)
            float4 cq = xp[g0 + pt];                     // L1-hot
            sm.f.dif[k][0][pt] = __fsub_rn(nq.x, cq.x);
            sm.f.dif[k][1][pt] = __fsub_rn(nq.y, cq.y);
            sm.f.dif[k][2][pt] = __fsub_rn(nq.z, cq.z);
        }
    }
    __syncthreads();

    float dx[KNB], dy[KNB], dz[KNB];
#pragma unroll
    for (int k = 0; k < KNB; ++k) {                      // conflict-free LDS
        dx[k] = sm.f.dif[k][0][lane];
        dy[k] = sm.f.dif[k][1][lane];
        dz[k] = sm.f.dif[k][2][lane];
    }

    // conv1 eighth: channels [8*wv, 8*wv+8)
    const float4* w1fv = (const float4*)w1f;
#pragma unroll 1
    for (int cc = 0; cc < 8; ++cc) {
        int c = wv * 8 + cc;                             // uniform -> s_load
        float4 wa = w1fv[c * 2];                         // {W0,W1,W2,W3}
        float4 wb = w1fv[c * 2 + 1];                     // {W4,W5,B1',pad}
        float base = wb.z + wa.w * cx + wb.x * cy + wb.y * cz;
        float m1 = -INFINITY, s = 0.f;
#pragma unroll
        for (int k = 0; k < KNB; ++k) {
            float h = fmaf(dz[k], wa.z, fmaf(dy[k], wa.y, fmaf(dx[k], wa.x, base)));
            float r = fmaxf(0.f, h);
            m1 = fmaxf(m1, r);
            s += r;
        }
        sm.f.cat[c * 64 + lane]        = m1;
        sm.f.cat[(64 + c) * 64 + lane] = s / 20.0f;
    }
    __syncthreads();

    const size_t SEC = (size_t)NB * 64 * NPB;   // elements per output section

    // write m1/m2 rows straight from cat (coalesced 256B rows)
#pragma unroll 1
    for (int q = 0; q < 16; ++q) {
        int r  = wv * 16 + q;                   // 0..127, uniform
        int ch = r & 63;
        float* dst = out + SEC * (1 + (r >> 6)) + ((size_t)b * 64 + ch) * NPB + n0;
        dst[lane] = sm.f.cat[r * 64 + lane];
    }

    // conv2 eighth: outputs [8*wv, 8*wv+8)
    const int ob = wv * 8;                      // uniform -> s_load weights
    float acc[8];
#pragma unroll
    for (int j = 0; j < 8; ++j) acc[j] = w2b[ob + j];
#pragma unroll 4
    for (int c = 0; c < 128; ++c) {
        float v = sm.f.cat[c * 64 + lane];
        const float4* wr = (const float4*)(w2f + c * 64 + ob);
        float4 q0 = wr[0], q1 = wr[1];
        acc[0] = fmaf(v, q0.x, acc[0]);  acc[1] = fmaf(v, q0.y, acc[1]);
        acc[2] = fmaf(v, q0.z, acc[2]);  acc[3] = fmaf(v, q0.w, acc[3]);
        acc[4] = fmaf(v, q1.x, acc[4]);  acc[5] = fmaf(v, q1.y, acc[5]);
        acc[6] = fmaf(v, q1.z, acc[6]);  acc[7] = fmaf(v, q1.w, acc[7]);
    }
#pragma unroll
    for (int j = 0; j < 8; ++j) acc[j] = fmaxf(0.f, acc[j]);

    __syncthreads();                            // all waves done reading cat
#pragma unroll
    for (int j = 0; j < 8; ++j) sm.f.cat[(ob + j) * 64 + lane] = acc[j];
    __syncthreads();
#pragma unroll 1
    for (int q = 0; q < 8; ++q) {
        int oo = wv * 8 + q;
        out[((size_t)b * 64 + oo) * NPB + n0 + lane] = sm.f.cat[oo * 64 + lane];
    }
}

extern "C" void kernel_launch(void* const* d_in, const int* in_sizes, int n_in,
                              void* d_out, int out_size, void* d_ws, size_t ws_size,
                              hipStream_t stream) {
    const float* x   = (const float*)d_in[0];
    const float* w1  = (const float*)d_in[1];
    const float* b1  = (const float*)d_in[2];
    const float* g1  = (const float*)d_in[3];
    const float* be1 = (const float*)d_in[4];
    const float* rm1 = (const float*)d_in[5];
    const float* rv1 = (const float*)d_in[6];
    const float* w2  = (const float*)d_in[7];
    const float* b2  = (const float*)d_in[8];
    const float* g2  = (const float*)d_in[9];
    const float* be2 = (const float*)d_in[10];
    const float* rm2 = (const float*)d_in[11];
    const float* rv2 = (const float*)d_in[12];

    char*   ws  = (char*)d_ws;
    float4* xp  = (float4*)ws;                      // 512 KB
    float*  w1f = (float*)(ws + 512 * 1024);        // 2 KB
    float*  w2f = w1f + 64 * 8;                     // 32 KB
    float*  w2b = w2f + 64 * 128;                   // 256 B

    pack_prep_kernel<<<NPTS / 256, 256, 0, stream>>>(
        x, xp, w1, b1, g1, be1, rm1, rv1, w2, b2, g2, be2, rm2, rv2,
        w1f, w2f, w2b);
    knnfuse_kernel<<<NPTS / 64, 512, 0, stream>>>(xp, w1f, w2f, w2b,
                                                  (float*)d_out);
}

// Round 6
// 248.875 us; speedup vs baseline: 1.0509x; 1.0509x over previous
//
#include <hip/hip_runtime.h>
#include <cstddef>

#define NPB  4096            // points per batch
#define KNB  20              // neighbors
#define NB   8               // batches
#define NPTS (NB * NPB)      // 32768 total points
#define NSEG 8               // segment-waves per block
#define SEGW 512             // candidates per segment
#define NSLOT 16             // push-buffer slots per thread

// ---------------------------------------------------------------------------
// Kernel A+P (R15): pack (x,y,z,xx) float4 + BN fold.
// R15 fix: w2f transpose-fold was block-0-only with stride-512B gather reads
// (64 cache lines per wave-load, 32 serial latency-bound iters, 255 CUs idle
// -> ~40us serial tail before knnfuse could start). Now: blocks 0..15 each
// fold 512 elements with LINEAR coalesced reads and scattered WRITES
// (fire-and-forget). Identical arithmetic per element.
// ---------------------------------------------------------------------------
__global__ __launch_bounds__(256) void pack_prep_kernel(
    const float* __restrict__ x, float4* __restrict__ xp,
    const float* __restrict__ w1, const float* __restrict__ b1,
    const float* __restrict__ g1, const float* __restrict__ be1,
    const float* __restrict__ rm1, const float* __restrict__ rv1,
    const float* __restrict__ w2, const float* __restrict__ b2,
    const float* __restrict__ g2, const float* __restrict__ be2,
    const float* __restrict__ rm2, const float* __restrict__ rv2,
    float* __restrict__ w1f, float* __restrict__ w2f, float* __restrict__ w2b)
{
    const int tid = threadIdx.x;
    const int g = blockIdx.x * 256 + tid;
    const int b = g >> 12, n = g & (NPB - 1);
    const float* xb = x + (size_t)b * 3 * NPB;
    float a0 = xb[n], a1 = xb[NPB + n], a2 = xb[2 * NPB + n];
    float xx = __fadd_rn(__fadd_rn(__fmul_rn(a0, a0), __fmul_rn(a1, a1)),
                         __fmul_rn(a2, a2));
    xp[g] = make_float4(a0, a1, a2, xx);

    if (blockIdx.x == 0 && tid < 64) {
        float sc1 = g1[tid] * rsqrtf(rv1[tid] + 1e-5f);
        float sh1 = be1[tid] - rm1[tid] * sc1;
#pragma unroll
        for (int j = 0; j < 6; ++j) w1f[tid * 8 + j] = sc1 * w1[tid * 6 + j];
        w1f[tid * 8 + 6] = sc1 * b1[tid] + sh1;
        w1f[tid * 8 + 7] = 0.f;
        float sc2 = g2[tid] * rsqrtf(rv2[tid] + 1e-5f);
        w2b[tid] = sc2 * b2[tid] + (be2[tid] - rm2[tid] * sc2);
    }
    // w2f fold spread over blocks 0..15: coalesced linear reads of w2,
    // scattered writes to the transposed w2f layout [c][o].
    if (blockIdx.x < 16) {
#pragma unroll
        for (int r = 0; r < 2; ++r) {
            int j = blockIdx.x * 512 + r * 256 + tid;   // linear index into w2
            int o = j >> 7, c = j & 127;                // w2[o][c]
            float sc2 = g2[o] * rsqrtf(rv2[o] + 1e-5f);
            w2f[c * 64 + o] = sc2 * w2[j];
        }
    }
}

// ---------------------------------------------------------------------------
// Kernel B+C merged (R11 EXACT — measured best 183.3us, VALUBusy 73%):
// exact top-20 SET per point + fused conv epilogue. Block = 512 thr = 64
// points x 8 segment-waves (wave-uniform candidate stream -> s_load).
// Ping-pong candidate prefetch across all unroll-1 backedges; flush reads
// one push-slot ahead. R12 (bitmask phase B) and R14 (idx-carry network)
// both measured worse — wave-uniform streamed re-scan + 2-op value network
// is the validated optimum so far.
// ---------------------------------------------------------------------------
union KSMem {
    float buf[NSLOT][512];          // 32 KB scan push buffers [slot][tid]
    float vals[NSEG][KNB][64];      // 40 KB sorted partial lists [wave][j][pt]
    struct {
        int list[NSEG][64][21];     // 42 KB survivors idx|(strict<<31)
        int cnt[NSEG][64];          //  2 KB
    } b;                            // 44 KB
    struct {
        float cat[128 * 64];        // 32 KB [c][pt]: c<64 m1, c>=64 m2
        float dif[KNB][3][64];      // 15 KB [k][coord][pt]
    } f;                            // 47 KB  (union = 47 KB)
};

__global__ __launch_bounds__(512, 4) void knnfuse_kernel(
    const float4* __restrict__ xp,
    const float* __restrict__ w1f, const float* __restrict__ w2f,
    const float* __restrict__ w2b, float* __restrict__ out)
{
    __shared__ KSMem sm;
    __shared__ float share[NSEG][64];   // 2 KB cross-wave vmins
    __shared__ int   outk[KNB][64];     // 5 KB final neighbor idx [k][pt]

    const int tid  = threadIdx.x;
    const int wv   = __builtin_amdgcn_readfirstlane(tid >> 6);
    const int lane = tid & 63;
    const int g0   = blockIdx.x * 64;
    const int b    = g0 >> 12;
    const int n0   = g0 & (NPB - 1);

    share[wv][lane] = -INFINITY;
    __syncthreads();

    const float4 me = xp[g0 + lane];                 // coalesced
    const float cx = me.x, cy = me.y, cz = me.z, xxn = me.w;

    auto dist = [&](float4 q) -> float {
        float inner = __fadd_rn(__fadd_rn(__fmul_rn(cx, q.x), __fmul_rn(cy, q.y)),
                                __fmul_rn(cz, q.z));
        return __fsub_rn(__fsub_rn(__fmul_rn(2.0f, inner), xxn), q.w);
    };

    float vals[KNB];
#pragma unroll
    for (int j = 0; j < KNB; ++j) vals[j] = -INFINITY;

    const float4* cand = xp + (b << 12) + wv * SEGW; // wave-uniform -> s_load

    // warm-up: direct sorted insert of first 20 candidates (1-ahead prefetch)
    {
        float4 cw = cand[0];
#pragma unroll 1
        for (int i = 0; i < KNB; ++i) {
            float4 nxt = cand[i + 1];                // i+1 <= 20 < SEGW: safe
            float cv = dist(cw);
#pragma unroll
            for (int j = 0; j < KNB; ++j) {
                float nv = fmaxf(cv, vals[j]);
                cv       = fminf(cv, vals[j]);
                vals[j]  = nv;
            }
            cw = nxt;
        }
    }
    float vmin = vals[KNB - 1];
    float thr  = vmin;
    int   cnt  = 0;

    auto flush = [&]() {
        float cv = sm.buf[0][tid];                   // speculative 1-ahead
#pragma unroll
        for (int j = 0; j < NSLOT; ++j) {
            if (!__any(j < cnt)) break;
            float nxt = (j + 1 < NSLOT) ? sm.buf[j + 1][tid] : -INFINITY;
            float c = (j < cnt) ? cv : -INFINITY;
#pragma unroll
            for (int q = 0; q < KNB; ++q) {          // 2-op step: max/min
                float nv = fmaxf(c, vals[q]);
                c        = fminf(c, vals[q]);
                vals[q]  = nv;
            }
            cv = nxt;
        }
        vmin = vals[KNB - 1];
        cnt = 0;
        thr = fmaxf(thr, vmin);
    };

    // remainder of first 64-cand chunk, buffered (<=12 resident + 4 = 16)
    {
        float4 c4[4];
#pragma unroll
        for (int u = 0; u < 4; ++u) c4[u] = cand[KNB + u];
#pragma unroll 1
        for (int i = KNB; i < 64; i += 4) {
            float4 n4[4];
            const int nx = (i + 4 < 64) ? i + 4 : KNB;   // clamp: safe reload
#pragma unroll
            for (int u = 0; u < 4; ++u) n4[u] = cand[nx + u];
#pragma unroll
            for (int u = 0; u < 4; ++u) {
                float d = dist(c4[u]);
                if (d > thr) { sm.buf[cnt][tid] = d; ++cnt; }
            }
            if (__any(cnt >= 13)) flush();
#pragma unroll
            for (int u = 0; u < 4; ++u) c4[u] = n4[u];
        }
    }
    flush();                                         // leave cnt=0 for main

    // main scan: threshold refresh every 32, flush check every 8,
    // ping-pong 8-wide candidate prefetch across the backedge
    {
        float4 ca[8], cb[8];
#pragma unroll
        for (int u = 0; u < 8; ++u) ca[u] = cand[64 + u];
#pragma unroll 1
        for (int i = 64; i < SEGW; i += 16) {
#pragma unroll
            for (int u = 0; u < 8; ++u) cb[u] = cand[i + 8 + u];
            if ((i & 31) == 0) {
                share[wv][lane] = vmin;              // racy: stale = safe
                float mx = share[0][lane];
#pragma unroll
                for (int w = 1; w < NSEG; ++w) mx = fmaxf(mx, share[w][lane]);
                thr = fmaxf(thr, mx);
            }
#pragma unroll
            for (int u = 0; u < 8; ++u) {
                float d = dist(ca[u]);
                if (d > thr) { sm.buf[cnt][tid] = d; ++cnt; }
            }
            if (__any(cnt >= 9)) flush();            // <=8 resident + 8 = 16
            const int nx = (i + 16 < SEGW) ? i + 16 : 64;  // clamp: safe
#pragma unroll
            for (int u = 0; u < 8; ++u) ca[u] = cand[nx + u];
#pragma unroll
            for (int u = 0; u < 8; ++u) {
                float d = dist(cb[u]);
                if (d > thr) { sm.buf[cnt][tid] = d; ++cnt; }
            }
            if (__any(cnt >= 9)) flush();
        }
    }
    flush();
    __syncthreads();                                 // retire push buffers

#pragma unroll
    for (int j = 0; j < KNB; ++j) sm.vals[wv][j][lane] = vals[j];
    __syncthreads();

    // every wave redundantly merges the 8 sorted value lists -> t (20th)
    float t = -INFINITY;
    {
        int p0 = 0, p1 = 0, p2 = 0, p3 = 0, p4 = 0, p5 = 0, p6 = 0, p7 = 0;
#pragma unroll 1
        for (int k = 0; k < KNB; ++k) {
            float e0 = sm.vals[0][p0][lane], e1 = sm.vals[1][p1][lane];
            float e2 = sm.vals[2][p2][lane], e3 = sm.vals[3][p3][lane];
            float e4 = sm.vals[4][p4][lane], e5 = sm.vals[5][p5][lane];
            float e6 = sm.vals[6][p6][lane], e7 = sm.vals[7][p7][lane];
            float bv = e0; int bs = 0;
            if (e1 > bv) { bv = e1; bs = 1; }
            if (e2 > bv) { bv = e2; bs = 2; }
            if (e3 > bv) { bv = e3; bs = 3; }
            if (e4 > bv) { bv = e4; bs = 4; }
            if (e5 > bv) { bv = e5; bs = 5; }
            if (e6 > bv) { bv = e6; bs = 6; }
            if (e7 > bv) { bv = e7; bs = 7; }
            t = bv;
            p0 += (bs == 0); p1 += (bs == 1); p2 += (bs == 2); p3 += (bs == 3);
            p4 += (bs == 4); p5 += (bs == 5); p6 += (bs == 6); p7 += (bs == 7);
        }
    }
    __syncthreads();                                 // retire vals (alias b)

    // phase B: collect survivors d >= t (idx | strict-bit), wave-uniform
    // streamed re-scan with ping-pong prefetch (R11-validated)
    int myc = 0;
    {
        float4 ca[8], cb[8];
#pragma unroll
        for (int u = 0; u < 8; ++u) ca[u] = cand[u];
#pragma unroll 1
        for (int i = 0; i < SEGW; i += 16) {
#pragma unroll
            for (int u = 0; u < 8; ++u) cb[u] = cand[i + 8 + u];
#pragma unroll
            for (int u = 0; u < 8; ++u) {
                float d = dist(ca[u]);
                if (d >= t) {
                    if (myc < KNB)
                        sm.b.list[wv][lane][myc] =
                            (wv * SEGW + i + u) | ((d > t) ? (int)0x80000000 : 0);
                    ++myc;
                }
            }
            const int nx = (i + 16 < SEGW) ? i + 16 : 0;   // clamp: safe
#pragma unroll
            for (int u = 0; u < 8; ++u) ca[u] = cand[nx + u];
#pragma unroll
            for (int u = 0; u < 8; ++u) {
                float d = dist(cb[u]);
                if (d >= t) {
                    if (myc < KNB)
                        sm.b.list[wv][lane][myc] =
                            (wv * SEGW + i + 8 + u) | ((d > t) ? (int)0x80000000 : 0);
                    ++myc;
                }
            }
        }
    }
    sm.b.cnt[wv][lane] = (myc < KNB) ? myc : KNB;
    __syncthreads();

    if (wv == 0) {
        int nout = 0;
#pragma unroll 1
        for (int pass = 0; pass < 2; ++pass) {       // 0: d>t, 1: d==t
#pragma unroll 1
            for (int w = 0; w < NSEG; ++w) {
                int cw = sm.b.cnt[w][lane];
#pragma unroll 1
                for (int j = 0; j < KNB; ++j) {
                    if (!__any(j < cw)) break;
                    if (j < cw) {
                        int e = sm.b.list[w][lane][j];
                        bool strict = (e < 0);
                        bool take = (pass == 0) ? strict : !strict;
                        if (take && nout < KNB) {
                            outk[nout][lane] = e & 0x7fffffff;
                            ++nout;
                        }
                    }
                }
            }
        }
    }
    __syncthreads();                                 // outk ready; b dead

    // ------------------- fused conv epilogue (R9-validated) -----------------
#pragma unroll
    for (int r = 0; r < 3; ++r) {
        int p = tid + r * 512;
        if (p < KNB * 64) {
            int k = p >> 6, pt = p & 63;
            int nb = outk[k][pt];
            float4 nq = xp[(b << 12) + nb];              // scattered (spread)
            float4 cq = xp[g0 + pt];                     // L1-hot
            sm.f.dif[k][0][pt] = __fsub_rn(nq.x, cq.x);
            sm.f.dif[k][1][pt] = __fsub_rn(nq.y, cq.y);
            sm.f.dif[k][2][pt] = __fsub_rn(nq.z, cq.z);
        }
    }
    __syncthreads();

    float dx[KNB], dy[KNB], dz[KNB];
#pragma unroll
    for (int k = 0; k < KNB; ++k) {                      // conflict-free LDS
        dx[k] = sm.f.dif[k][0][lane];
        dy[k] = sm.f.dif[k][1][lane];
        dz[k] = sm.f.dif[k][2][lane];
    }

    // conv1 eighth: channels [8*wv, 8*wv+8)
    const float4* w1fv = (const float4*)w1f;
#pragma unroll 1
    for (int cc = 0; cc < 8; ++cc) {
        int c = wv * 8 + cc;                             // uniform -> s_load
        float4 wa = w1fv[c * 2];                         // {W0,W1,W2,W3}
        float4 wb = w1fv[c * 2 + 1];                     // {W4,W5,B1',pad}
        float base = wb.z + wa.w * cx + wb.x * cy + wb.y * cz;
        float m1 = -INFINITY, s = 0.f;
#pragma unroll
        for (int k = 0; k < KNB; ++k) {
            float h = fmaf(dz[k], wa.z, fmaf(dy[k], wa.y, fmaf(dx[k], wa.x, base)));
            float r = fmaxf(0.f, h);
            m1 = fmaxf(m1, r);
            s += r;
        }
        sm.f.cat[c * 64 + lane]        = m1;
        sm.f.cat[(64 + c) * 64 + lane] = s / 20.0f;
    }
    __syncthreads();

    const size_t SEC = (size_t)NB * 64 * NPB;   // elements per output section

    // write m1/m2 rows straight from cat (coalesced 256B rows)
#pragma unroll 1
    for (int q = 0; q < 16; ++q) {
        int r  = wv * 16 + q;                   // 0..127, uniform
        int ch = r & 63;
        float* dst = out + SEC * (1 + (r >> 6)) + ((size_t)b * 64 + ch) * NPB + n0;
        dst[lane] = sm.f.cat[r * 64 + lane];
    }

    // conv2 eighth: outputs [8*wv, 8*wv+8)
    const int ob = wv * 8;                      // uniform -> s_load weights
    float acc[8];
#pragma unroll
    for (int j = 0; j < 8; ++j) acc[j] = w2b[ob + j];
#pragma unroll 4
    for (int c = 0; c < 128; ++c) {
        float v = sm.f.cat[c * 64 + lane];
        const float4* wr = (const float4*)(w2f + c * 64 + ob);
        float4 q0 = wr[0], q1 = wr[1];
        acc[0] = fmaf(v, q0.x, acc[0]);  acc[1] = fmaf(v, q0.y, acc[1]);
        acc[2] = fmaf(v, q0.z, acc[2]);  acc[3] = fmaf(v, q0.w, acc[3]);
        acc[4] = fmaf(v, q1.x, acc[4]);  acc[5] = fmaf(v, q1.y, acc[5]);
        acc[6] = fmaf(v, q1.z, acc[6]);  acc[7] = fmaf(v, q1.w, acc[7]);
    }
#pragma unroll
    for (int j = 0; j < 8; ++j) acc[j] = fmaxf(0.f, acc[j]);

    __syncthreads();                            // all waves done reading cat
#pragma unroll
    for (int j = 0; j < 8; ++j) sm.f.cat[(ob + j) * 64 + lane] = acc[j];
    __syncthreads();
#pragma unroll 1
    for (int q = 0; q < 8; ++q) {
        int oo = wv * 8 + q;
        out[((size_t)b * 64 + oo) * NPB + n0 + lane] = sm.f.cat[oo * 64 + lane];
    }
}

extern "C" void kernel_launch(void* const* d_in, const int* in_sizes, int n_in,
                              void* d_out, int out_size, void* d_ws, size_t ws_size,
                              hipStream_t stream) {
    const float* x   = (const float*)d_in[0];
    const float* w1  = (const float*)d_in[1];
    const float* b1  = (const float*)d_in[2];
    const float* g1  = (const float*)d_in[3];
    const float* be1 = (const float*)d_in[4];
    const float* rm1 = (const float*)d_in[5];
    const float* rv1 = (const float*)d_in[6];
    const float* w2  = (const float*)d_in[7];
    const float* b2  = (const float*)d_in[8];
    const float* g2  = (const float*)d_in[9];
    const float* be2 = (const float*)d_in[10];
    const float* rm2 = (const float*)d_in[11];
    const float* rv2 = (const float*)d_in[12];

    char*   ws  = (char*)d_ws;
    float4* xp  = (float4*)ws;                      // 512 KB
    float*  w1f = (float*)(ws + 512 * 1024);        // 2 KB
    float*  w2f = w1f + 64 * 8;                     // 32 KB
    float*  w2b = w2f + 64 * 128;                   // 256 B

    pack_prep_kernel<<<NPTS / 256, 256, 0, stream>>>(
        x, xp, w1, b1, g1, be1, rm1, rv1, w2, b2, g2, be2, rm2, rv2,
        w1f, w2f, w2b);
    knnfuse_kernel<<<NPTS / 64, 512, 0, stream>>>(xp, w1f, w2f, w2b,
                                                  (float*)d_out);
}

// Round 7
// 237.352 us; speedup vs baseline: 1.1020x; 1.0485x over previous
//
#include <hip/hip_runtime.h>
#include <cstddef>

#define NPB  4096            // points per batch
#define KNB  20              // neighbors
#define NB   8               // batches
#define NPTS (NB * NPB)      // 32768 total points
#define NSEG 8               // segment-waves per block
#define SEGW 512             // candidates per segment
#define NSLOT 16             // push-buffer slots per thread

// ---------------------------------------------------------------------------
// Kernel A+P (R15-validated): pack (x,y,z,xx) float4 + BN fold, w2f fold
// spread over 16 blocks with coalesced reads / scattered writes.
// ---------------------------------------------------------------------------
__global__ __launch_bounds__(256) void pack_prep_kernel(
    const float* __restrict__ x, float4* __restrict__ xp,
    const float* __restrict__ w1, const float* __restrict__ b1,
    const float* __restrict__ g1, const float* __restrict__ be1,
    const float* __restrict__ rm1, const float* __restrict__ rv1,
    const float* __restrict__ w2, const float* __restrict__ b2,
    const float* __restrict__ g2, const float* __restrict__ be2,
    const float* __restrict__ rm2, const float* __restrict__ rv2,
    float* __restrict__ w1f, float* __restrict__ w2f, float* __restrict__ w2b)
{
    const int tid = threadIdx.x;
    const int g = blockIdx.x * 256 + tid;
    const int b = g >> 12, n = g & (NPB - 1);
    const float* xb = x + (size_t)b * 3 * NPB;
    float a0 = xb[n], a1 = xb[NPB + n], a2 = xb[2 * NPB + n];
    float xx = __fadd_rn(__fadd_rn(__fmul_rn(a0, a0), __fmul_rn(a1, a1)),
                         __fmul_rn(a2, a2));
    xp[g] = make_float4(a0, a1, a2, xx);

    if (blockIdx.x == 0 && tid < 64) {
        float sc1 = g1[tid] * rsqrtf(rv1[tid] + 1e-5f);
        float sh1 = be1[tid] - rm1[tid] * sc1;
#pragma unroll
        for (int j = 0; j < 6; ++j) w1f[tid * 8 + j] = sc1 * w1[tid * 6 + j];
        w1f[tid * 8 + 6] = sc1 * b1[tid] + sh1;
        w1f[tid * 8 + 7] = 0.f;
        float sc2 = g2[tid] * rsqrtf(rv2[tid] + 1e-5f);
        w2b[tid] = sc2 * b2[tid] + (be2[tid] - rm2[tid] * sc2);
    }
    if (blockIdx.x < 16) {
#pragma unroll
        for (int r = 0; r < 2; ++r) {
            int j = blockIdx.x * 512 + r * 256 + tid;   // linear index into w2
            int o = j >> 7, c = j & 127;                // w2[o][c]
            float sc2 = g2[o] * rsqrtf(rv2[o] + 1e-5f);
            w2f[c * 64 + o] = sc2 * w2[j];
        }
    }
}

// ---------------------------------------------------------------------------
// Kernel B+C merged. R16 = R11 structure (measured best) + two flush-cost
// levers derived from the R11/R14 A/B (flush = ~230 wave-paced slot-passes
// x 40 ops = ~half of all VALU work):
//  (J) tighter push threshold: besides max_w(v20_w), share v10/v5 per wave
//      and use pair/quad union bounds (2x10, 4x5 >= 20 elements) — all are
//      valid lower bounds on the global 20th t (monotone lists => racy-safe),
//      so exactness of the t / phase-B argument is unchanged; only fewer
//      non-survivors get pushed.
//  (K) stale-slot skip: inserting c <= vals[19] leaves the top-20 VALUES
//      unchanged (the d==20th case drops an equal value), so a slot where
//      no lane beats its 20th skips the 40-op network for 3 ops.
// ---------------------------------------------------------------------------
union KSMem {
    float buf[NSLOT][512];          // 32 KB scan push buffers [slot][tid]
    float vals[NSEG][KNB][64];      // 40 KB sorted partial lists [wave][j][pt]
    struct {
        int list[NSEG][64][21];     // 42 KB survivors idx|(strict<<31)
        int cnt[NSEG][64];          //  2 KB
    } b;                            // 44 KB
    struct {
        float cat[128 * 64];        // 32 KB [c][pt]: c<64 m1, c>=64 m2
        float dif[KNB][3][64];      // 15 KB [k][coord][pt]
    } f;                            // 47 KB  (union = 47 KB)
};

__global__ __launch_bounds__(512, 4) void knnfuse_kernel(
    const float4* __restrict__ xp,
    const float* __restrict__ w1f, const float* __restrict__ w2f,
    const float* __restrict__ w2b, float* __restrict__ out)
{
    __shared__ KSMem sm;
    __shared__ float4 shareV[NSEG][64]; // 8 KB {v20, v10, v5, -} per wave/pt
    __shared__ int   outk[KNB][64];     // 5 KB final neighbor idx [k][pt]

    const int tid  = threadIdx.x;
    const int wv   = __builtin_amdgcn_readfirstlane(tid >> 6);
    const int lane = tid & 63;
    const int g0   = blockIdx.x * 64;
    const int b    = g0 >> 12;
    const int n0   = g0 & (NPB - 1);

    shareV[wv][lane] = make_float4(-INFINITY, -INFINITY, -INFINITY, -INFINITY);
    __syncthreads();

    const float4 me = xp[g0 + lane];                 // coalesced
    const float cx = me.x, cy = me.y, cz = me.z, xxn = me.w;

    auto dist = [&](float4 q) -> float {
        float inner = __fadd_rn(__fadd_rn(__fmul_rn(cx, q.x), __fmul_rn(cy, q.y)),
                                __fmul_rn(cz, q.z));
        return __fsub_rn(__fsub_rn(__fmul_rn(2.0f, inner), xxn), q.w);
    };

    float vals[KNB];
#pragma unroll
    for (int j = 0; j < KNB; ++j) vals[j] = -INFINITY;

    const float4* cand = xp + (b << 12) + wv * SEGW; // wave-uniform -> s_load

    // warm-up: direct sorted insert of first 20 candidates (1-ahead prefetch)
    {
        float4 cw = cand[0];
#pragma unroll 1
        for (int i = 0; i < KNB; ++i) {
            float4 nxt = cand[i + 1];                // i+1 <= 20 < SEGW: safe
            float cv = dist(cw);
#pragma unroll
            for (int j = 0; j < KNB; ++j) {
                float nv = fmaxf(cv, vals[j]);
                cv       = fminf(cv, vals[j]);
                vals[j]  = nv;
            }
            cw = nxt;
        }
    }
    float vmin = vals[KNB - 1];
    float thr  = vmin;
    int   cnt  = 0;

    // (J) publish {v20,v10,v5} and tighten thr with union bounds.
    // racy by design: stale stats are older (smaller) -> still <= t.
    auto refresh = [&]() {
        shareV[wv][lane] = make_float4(vmin, vals[9], vals[4], 0.f);
        float4 s0 = shareV[0][lane], s1 = shareV[1][lane];
        float4 s2 = shareV[2][lane], s3 = shareV[3][lane];
        float4 s4 = shareV[4][lane], s5 = shareV[5][lane];
        float4 s6 = shareV[6][lane], s7 = shareV[7][lane];
        // 20 elems >= max of per-wave 20ths
        float m19 = fmaxf(fmaxf(fmaxf(s0.x, s1.x), fmaxf(s2.x, s3.x)),
                          fmaxf(fmaxf(s4.x, s5.x), fmaxf(s6.x, s7.x)));
        // pair bound: 2 waves x 10 elems >= min(v10 pair)
        float b9 = fmaxf(fmaxf(fminf(s0.y, s1.y), fminf(s2.y, s3.y)),
                         fmaxf(fminf(s4.y, s5.y), fminf(s6.y, s7.y)));
        // quad bound: 4 waves x 5 elems >= min(v5 quad)
        float q0 = fminf(fminf(s0.z, s1.z), fminf(s2.z, s3.z));
        float q1 = fminf(fminf(s4.z, s5.z), fminf(s6.z, s7.z));
        float b4 = fmaxf(q0, q1);
        thr = fmaxf(fmaxf(thr, m19), fmaxf(b9, b4));
    };
    refresh();                                       // early seed (lists full)

    auto flush = [&]() {
        float cv = sm.buf[0][tid];                   // speculative 1-ahead
#pragma unroll
        for (int j = 0; j < NSLOT; ++j) {
            if (!__any(j < cnt)) break;
            float nxt = (j + 1 < NSLOT) ? sm.buf[j + 1][tid] : -INFINITY;
            float c = (j < cnt) ? cv : -INFINITY;
            if (__any(c > vals[KNB - 1])) {          // (K) stale-slot skip
#pragma unroll
                for (int q = 0; q < KNB; ++q) {      // 2-op step: max/min
                    float nv = fmaxf(c, vals[q]);
                    c        = fminf(c, vals[q]);
                    vals[q]  = nv;
                }
            }
            cv = nxt;
        }
        vmin = vals[KNB - 1];
        cnt = 0;
        thr = fmaxf(thr, vmin);
    };

    // remainder of first 64-cand chunk, buffered (<=12 resident + 4 = 16)
    {
        float4 c4[4];
#pragma unroll
        for (int u = 0; u < 4; ++u) c4[u] = cand[KNB + u];
#pragma unroll 1
        for (int i = KNB; i < 64; i += 4) {
            float4 n4[4];
            const int nx = (i + 4 < 64) ? i + 4 : KNB;   // clamp: safe reload
#pragma unroll
            for (int u = 0; u < 4; ++u) n4[u] = cand[nx + u];
            if ((i & 15) == 4) refresh();            // i = 36, 52 (early flood)
#pragma unroll
            for (int u = 0; u < 4; ++u) {
                float d = dist(c4[u]);
                if (d > thr) { sm.buf[cnt][tid] = d; ++cnt; }
            }
            if (__any(cnt >= 13)) flush();
#pragma unroll
            for (int u = 0; u < 4; ++u) c4[u] = n4[u];
        }
    }
    flush();                                         // leave cnt=0 for main

    // main scan: threshold refresh every 32, flush check every 8,
    // ping-pong 8-wide candidate prefetch across the backedge
    {
        float4 ca[8], cb[8];
#pragma unroll
        for (int u = 0; u < 8; ++u) ca[u] = cand[64 + u];
#pragma unroll 1
        for (int i = 64; i < SEGW; i += 16) {
#pragma unroll
            for (int u = 0; u < 8; ++u) cb[u] = cand[i + 8 + u];
            if ((i & 31) == 0) refresh();
#pragma unroll
            for (int u = 0; u < 8; ++u) {
                float d = dist(ca[u]);
                if (d > thr) { sm.buf[cnt][tid] = d; ++cnt; }
            }
            if (__any(cnt >= 9)) flush();            // <=8 resident + 8 = 16
            const int nx = (i + 16 < SEGW) ? i + 16 : 64;  // clamp: safe
#pragma unroll
            for (int u = 0; u < 8; ++u) ca[u] = cand[nx + u];
#pragma unroll
            for (int u = 0; u < 8; ++u) {
                float d = dist(cb[u]);
                if (d > thr) { sm.buf[cnt][tid] = d; ++cnt; }
            }
            if (__any(cnt >= 9)) flush();
        }
    }
    flush();
    __syncthreads();                                 // retire push buffers

#pragma unroll
    for (int j = 0; j < KNB; ++j) sm.vals[wv][j][lane] = vals[j];
    __syncthreads();

    // every wave redundantly merges the 8 sorted value lists -> t (20th)
    float t = -INFINITY;
    {
        int p0 = 0, p1 = 0, p2 = 0, p3 = 0, p4 = 0, p5 = 0, p6 = 0, p7 = 0;
#pragma unroll 1
        for (int k = 0; k < KNB; ++k) {
            float e0 = sm.vals[0][p0][lane], e1 = sm.vals[1][p1][lane];
            float e2 = sm.vals[2][p2][lane], e3 = sm.vals[3][p3][lane];
            float e4 = sm.vals[4][p4][lane], e5 = sm.vals[5][p5][lane];
            float e6 = sm.vals[6][p6][lane], e7 = sm.vals[7][p7][lane];
            float bv = e0; int bs = 0;
            if (e1 > bv) { bv = e1; bs = 1; }
            if (e2 > bv) { bv = e2; bs = 2; }
            if (e3 > bv) { bv = e3; bs = 3; }
            if (e4 > bv) { bv = e4; bs = 4; }
            if (e5 > bv) { bv = e5; bs = 5; }
            if (e6 > bv) { bv = e6; bs = 6; }
            if (e7 > bv) { bv = e7; bs = 7; }
            t = bv;
            p0 += (bs == 0); p1 += (bs == 1); p2 += (bs == 2); p3 += (bs == 3);
            p4 += (bs == 4); p5 += (bs == 5); p6 += (bs == 6); p7 += (bs == 7);
        }
    }
    __syncthreads();                                 // retire vals (alias b)

    // phase B: collect survivors d >= t (idx | strict-bit), wave-uniform
    // streamed re-scan with ping-pong prefetch (R11-validated)
    int myc = 0;
    {
        float4 ca[8], cb[8];
#pragma unroll
        for (int u = 0; u < 8; ++u) ca[u] = cand[u];
#pragma unroll 1
        for (int i = 0; i < SEGW; i += 16) {
#pragma unroll
            for (int u = 0; u < 8; ++u) cb[u] = cand[i + 8 + u];
#pragma unroll
            for (int u = 0; u < 8; ++u) {
                float d = dist(ca[u]);
                if (d >= t) {
                    if (myc < KNB)
                        sm.b.list[wv][lane][myc] =
                            (wv * SEGW + i + u) | ((d > t) ? (int)0x80000000 : 0);
                    ++myc;
                }
            }
            const int nx = (i + 16 < SEGW) ? i + 16 : 0;   // clamp: safe
#pragma unroll
            for (int u = 0; u < 8; ++u) ca[u] = cand[nx + u];
#pragma unroll
            for (int u = 0; u < 8; ++u) {
                float d = dist(cb[u]);
                if (d >= t) {
                    if (myc < KNB)
                        sm.b.list[wv][lane][myc] =
                            (wv * SEGW + i + 8 + u) | ((d > t) ? (int)0x80000000 : 0);
                    ++myc;
                }
            }
        }
    }
    sm.b.cnt[wv][lane] = (myc < KNB) ? myc : KNB;
    __syncthreads();

    if (wv == 0) {
        int nout = 0;
#pragma unroll 1
        for (int pass = 0; pass < 2; ++pass) {       // 0: d>t, 1: d==t
#pragma unroll 1
            for (int w = 0; w < NSEG; ++w) {
                int cw = sm.b.cnt[w][lane];
#pragma unroll 1
                for (int j = 0; j < KNB; ++j) {
                    if (!__any(j < cw)) break;
                    if (j < cw) {
                        int e = sm.b.list[w][lane][j];
                        bool strict = (e < 0);
                        bool take = (pass == 0) ? strict : !strict;
                        if (take && nout < KNB) {
                            outk[nout][lane] = e & 0x7fffffff;
                            ++nout;
                        }
                    }
                }
            }
        }
    }
    __syncthreads();                                 // outk ready; b dead

    // ------------------- fused conv epilogue (R9-validated) -----------------
#pragma unroll
    for (int r = 0; r < 3; ++r) {
        int p = tid + r * 512;
        if (p < KNB * 64) {
            int k = p >> 6, pt = p & 63;
            int nb = outk[k][pt];
            float4 nq = xp[(b << 12) + nb];              // scattered (spread)
            float4 cq = xp[g0 + pt];                     // L1-hot
            sm.f.dif[k][0][pt] = __fsub_rn(nq.x, cq.x);
            sm.f.dif[k][1][pt] = __fsub_rn(nq.y, cq.y);
            sm.f.dif[k][2][pt] = __fsub_rn(nq.z, cq.z);
        }
    }
    __syncthreads();

    float dx[KNB], dy[KNB], dz[KNB];
#pragma unroll
    for (int k = 0; k < KNB; ++k) {                      // conflict-free LDS
        dx[k] = sm.f.dif[k][0][lane];
        dy[k] = sm.f.dif[k][1][lane];
        dz[k] = sm.f.dif[k][2][lane];
    }

    // conv1 eighth: channels [8*wv, 8*wv+8)
    const float4* w1fv = (const float4*)w1f;
#pragma unroll 1
    for (int cc = 0; cc < 8; ++cc) {
        int c = wv * 8 + cc;                             // uniform -> s_load
        float4 wa = w1fv[c * 2];                         // {W0,W1,W2,W3}
        float4 wb = w1fv[c * 2 + 1];                     // {W4,W5,B1',pad}
        float base = wb.z + wa.w * cx + wb.x * cy + wb.y * cz;
        float m1 = -INFINITY, s = 0.f;
#pragma unroll
        for (int k = 0; k < KNB; ++k) {
            float h = fmaf(dz[k], wa.z, fmaf(dy[k], wa.y, fmaf(dx[k], wa.x, base)));
            float r = fmaxf(0.f, h);
            m1 = fmaxf(m1, r);
            s += r;
        }
        sm.f.cat[c * 64 + lane]        = m1;
        sm.f.cat[(64 + c) * 64 + lane] = s / 20.0f;
    }
    __syncthreads();

    const size_t SEC = (size_t)NB * 64 * NPB;   // elements per output section

    // write m1/m2 rows straight from cat (coalesced 256B rows)
#pragma unroll 1
    for (int q = 0; q < 16; ++q) {
        int r  = wv * 16 + q;                   // 0..127, uniform
        int ch = r & 63;
        float* dst = out + SEC * (1 + (r >> 6)) + ((size_t)b * 64 + ch) * NPB + n0;
        dst[lane] = sm.f.cat[r * 64 + lane];
    }

    // conv2 eighth: outputs [8*wv, 8*wv+8)
    const int ob = wv * 8;                      // uniform -> s_load weights
    float acc[8];
#pragma unroll
    for (int j = 0; j < 8; ++j) acc[j] = w2b[ob + j];
#pragma unroll 4
    for (int c = 0; c < 128; ++c) {
        float v = sm.f.cat[c * 64 + lane];
        const float4* wr = (const float4*)(w2f + c * 64 + ob);
        float4 q0 = wr[0], q1 = wr[1];
        acc[0] = fmaf(v, q0.x, acc[0]);  acc[1] = fmaf(v, q0.y, acc[1]);
        acc[2] = fmaf(v, q0.z, acc[2]);  acc[3] = fmaf(v, q0.w, acc[3]);
        acc[4] = fmaf(v, q1.x, acc[4]);  acc[5] = fmaf(v, q1.y, acc[5]);
        acc[6] = fmaf(v, q1.z, acc[6]);  acc[7] = fmaf(v, q1.w, acc[7]);
    }
#pragma unroll
    for (int j = 0; j < 8; ++j) acc[j] = fmaxf(0.f, acc[j]);

    __syncthreads();                            // all waves done reading cat
#pragma unroll
    for (int j = 0; j < 8; ++j) sm.f.cat[(ob + j) * 64 + lane] = acc[j];
    __syncthreads();
#pragma unroll 1
    for (int q = 0; q < 8; ++q) {
        int oo = wv * 8 + q;
        out[((size_t)b * 64 + oo) * NPB + n0 + lane] = sm.f.cat[oo * 64 + lane];
    }
}

extern "C" void kernel_launch(void* const* d_in, const int* in_sizes, int n_in,
                              void* d_out, int out_size, void* d_ws, size_t ws_size,
                              hipStream_t stream) {
    const float* x   = (const float*)d_in[0];
    const float* w1  = (const float*)d_in[1];
    const float* b1  = (const float*)d_in[2];
    const float* g1  = (const float*)d_in[3];
    const float* be1 = (const float*)d_in[4];
    const float* rm1 = (const float*)d_in[5];
    const float* rv1 = (const float*)d_in[6];
    const float* w2  = (const float*)d_in[7];
    const float* b2  = (const float*)d_in[8];
    const float* g2  = (const float*)d_in[9];
    const float* be2 = (const float*)d_in[10];
    const float* rm2 = (const float*)d_in[11];
    const float* rv2 = (const float*)d_in[12];

    char*   ws  = (char*)d_ws;
    float4* xp  = (float4*)ws;                      // 512 KB
    float*  w1f = (float*)(ws + 512 * 1024);        // 2 KB
    float*  w2f = w1f + 64 * 8;                     // 32 KB
    float*  w2b = w2f + 64 * 128;                   // 256 B

    pack_prep_kernel<<<NPTS / 256, 256, 0, stream>>>(
        x, xp, w1, b1, g1, be1, rm1, rv1, w2, b2, g2, be2, rm2, rv2,
        w1f, w2f, w2b);
    knnfuse_kernel<<<NPTS / 64, 512, 0, stream>>>(xp, w1f, w2f, w2b,
                                                  (float*)d_out);
}